// Round 4
// baseline (172.252 us; speedup 1.0000x reference)
//
#include <hip/hip_runtime.h>
#include <math.h>

#define IN_CH 128
#define OUT_CH 64
#define NEG_SLOPE 0.2f
#define CAP 64       // slots per node; mean degree 16, P(deg>64) ~ 1e-16 for uniform dst
#define NSHARD 8     // = XCD count; shard s committed only by blocks with bid%8==s
#define SCAN_EPT 16  // edges scanned per thread per cs block (4096/block)

typedef long long ll2 __attribute__((ext_vector_type(2)));
typedef int i4v __attribute__((ext_vector_type(4)));
typedef float f4v __attribute__((ext_vector_type(4)));
typedef unsigned short us4v __attribute__((ext_vector_type(4)));

// ---------- bf16 helpers ----------
__device__ __forceinline__ unsigned short f2bf(float f) {
    unsigned u = __float_as_uint(f);
    unsigned r = (u + 0x7FFFu + ((u >> 16) & 1u)) >> 16;   // round-nearest-even
    return (unsigned short)r;
}

// ---------- edge dtype sniff: int64 little-endian => odd int32 words are 0 ----------
__device__ __forceinline__ bool sniff_is64(const void* edges) {
    const unsigned* up = (const unsigned*)edges;
    bool is64 = true;
#pragma unroll
    for (int k = 0; k < 16; k++) is64 = is64 && (up[2 * k + 1] == 0u);
    return is64;
}

// ---------- K1: XCD-sharded count+scatter interleaved with mm ----------
// R0-R3 evidence: k1 is pinned at hbm_bytes/dur ~= 1.2 TB/s with WRITE_SIZE 54MB
// (payload only ~10MB) regardless of atomic MLP (EPT 2/4/8) or grid size -> the
// limiter is random-64B-line writeback amplification of the slot scatter: a node's
// slot line is dirtied from all 8 XCDs spread over the whole edge stream, so it
// does ~10 fetch/evict round trips through the non-coherent per-XCD L2s.
// Fix: shard by dst (shard = d*8/N). A cs block commits ONLY its shard's edges,
// shard = bid%8 -> XCD (HW round-robins blocks over XCDs). All writers of a slot
// line are then one XCD; the 1.6MB shard slot region is L2-resident and written
// back ONCE at kernel end. Edge dst column is scanned 8x (sequential nt, L3-served);
// src gathered once per edge (nt: zero reuse). x loads + h16 stores nt too: they
// have no reuse in k1 and would otherwise evict the slot lines we're protecting.
// Blocks grouped in 24 (16 cs + 8 mm): 24%8==0 keeps bid%8 == in-group position%8,
// preserving the shard->XCD mapping while co-scheduling mm waves to cover latency.
__global__ __launch_bounds__(256) void k_mm_cs(
        const float* __restrict__ x, const float* __restrict__ W,
        const float* __restrict__ att, unsigned short* __restrict__ h16,
        float* __restrict__ asrc, float* __restrict__ adst, int N,
        const void* __restrict__ edges, int* __restrict__ counts,
        int* __restrict__ slots, int* __restrict__ oflow_cnt,
        int2* __restrict__ oflow, int E, int groups) {
    __shared__ float Ws[IN_CH * OUT_CH];   // 32 KB (mm role only)
    int t = threadIdx.x;
    int bid = blockIdx.x;
    int role, id = 0, shard = 0, chunk = 0;
    if (bid >= groups * 24) {
        role = 0; id = 8 * groups + (bid - groups * 24);
    } else {
        int g = bid / 24, p = bid % 24;
        if (p < 16) { role = 1; shard = p & 7; chunk = g * 2 + (p >> 3); }
        else        { role = 0; id = g * 8 + (p - 16); }
    }

    if (role == 1) {
        // ----- sharded count+scatter -----
        int lo = (int)(((long long)shard * N) / NSHARD);
        int hi = (int)(((long long)(shard + 1) * N) / NSHARD);
        int base = chunk * (256 * SCAN_EPT) + t * SCAN_EPT;
        if (base >= E) return;
        bool is64 = sniff_is64(edges);
        int dv[SCAN_EPT];
        if (base + SCAN_EPT <= E) {
            if (is64) {
                const ll2* pd = (const ll2*)((const long long*)edges + (size_t)E + base);
#pragma unroll
                for (int i = 0; i < SCAN_EPT / 2; i++) {
                    ll2 w = __builtin_nontemporal_load(pd + i);
                    dv[2 * i] = (int)w.x; dv[2 * i + 1] = (int)w.y;
                }
            } else {
                const i4v* pd = (const i4v*)((const int*)edges + E + base);
#pragma unroll
                for (int i = 0; i < SCAN_EPT / 4; i++) {
                    i4v w = __builtin_nontemporal_load(pd + i);
                    dv[4 * i] = w.x; dv[4 * i + 1] = w.y;
                    dv[4 * i + 2] = w.z; dv[4 * i + 3] = w.w;
                }
            }
        } else {
            for (int i = 0; i < SCAN_EPT; i++) {
                int e = base + i;
                dv[i] = (e < E) ? (is64 ? (int)((const long long*)edges)[(size_t)E + e]
                                        : ((const int*)edges)[E + e])
                                : -1;
            }
        }
        // phase 1: gather srcs of matched edges (read exactly once globally -> nt)
        int sv[SCAN_EPT];
        unsigned mmask = 0;
#pragma unroll
        for (int i = 0; i < SCAN_EPT; i++) {
            int d = dv[i];
            bool m = (d >= lo) && (d < hi);
            if (m) {
                sv[i] = is64 ? (int)__builtin_nontemporal_load(
                                   (const long long*)edges + base + i)
                             : __builtin_nontemporal_load(
                                   (const int*)edges + base + i);
                mmask |= (1u << i);
            }
        }
        // phase 2: all count atomics issued back-to-back (MLP)
        int rr[SCAN_EPT];
#pragma unroll
        for (int i = 0; i < SCAN_EPT; i++)
            if (mmask & (1u << i)) rr[i] = atomicAdd(counts + dv[i], 1);
        // phase 3: slot stores -> shard-local L2-resident lines
#pragma unroll
        for (int i = 0; i < SCAN_EPT; i++) {
            if (mmask & (1u << i)) {
                if (rr[i] < CAP) {
                    slots[((size_t)dv[i] << 6) + rr[i]] = sv[i];
                } else {
                    int p2 = atomicAdd(oflow_cnt, 1);
                    oflow[p2] = make_int2(sv[i], dv[i]);
                }
            }
        }
        return;
    }

    // ----- mm path: 64 nodes/block, W staged in LDS, x/h16 non-temporal -----
    for (int i = t * 4; i < IN_CH * OUT_CH; i += 256 * 4)
        *(float4*)&Ws[i] = *(const float4*)&W[i];
    int cg = t & 15, g = t >> 4;
    float4 att_d = *(const float4*)&att[cg * 4];        // dst half: att[0:64]
    float4 att_s = *(const float4*)&att[64 + cg * 4];   // src half: att[64:128]
    __syncthreads();

    int n0 = id * 64 + g * 4;
    if (n0 >= N + 3 && id * 64 >= N) { /* surplus block: still safe via clamps */ }
    int nn[4];
#pragma unroll
    for (int m = 0; m < 4; m++) nn[m] = min(n0 + m, N - 1);

    float4 acc[4];
#pragma unroll
    for (int m = 0; m < 4; m++) acc[m] = make_float4(0.f, 0.f, 0.f, 0.f);

#pragma unroll 2
    for (int k4 = 0; k4 < IN_CH / 4; k4++) {
        f4v xv[4];
#pragma unroll
        for (int m = 0; m < 4; m++)
            xv[m] = __builtin_nontemporal_load(
                (const f4v*)&x[(size_t)nn[m] * IN_CH + k4 * 4]);
        float4 wv[4];
#pragma unroll
        for (int j = 0; j < 4; j++)
            wv[j] = *(const float4*)&Ws[(k4 * 4 + j) * OUT_CH + cg * 4];
#pragma unroll
        for (int m = 0; m < 4; m++) {
            acc[m].x = fmaf(xv[m].x, wv[0].x, acc[m].x);
            acc[m].y = fmaf(xv[m].x, wv[0].y, acc[m].y);
            acc[m].z = fmaf(xv[m].x, wv[0].z, acc[m].z);
            acc[m].w = fmaf(xv[m].x, wv[0].w, acc[m].w);
            acc[m].x = fmaf(xv[m].y, wv[1].x, acc[m].x);
            acc[m].y = fmaf(xv[m].y, wv[1].y, acc[m].y);
            acc[m].z = fmaf(xv[m].y, wv[1].z, acc[m].z);
            acc[m].w = fmaf(xv[m].y, wv[1].w, acc[m].w);
            acc[m].x = fmaf(xv[m].z, wv[2].x, acc[m].x);
            acc[m].y = fmaf(xv[m].z, wv[2].y, acc[m].y);
            acc[m].z = fmaf(xv[m].z, wv[2].z, acc[m].z);
            acc[m].w = fmaf(xv[m].z, wv[2].w, acc[m].w);
            acc[m].x = fmaf(xv[m].w, wv[3].x, acc[m].x);
            acc[m].y = fmaf(xv[m].w, wv[3].y, acc[m].y);
            acc[m].z = fmaf(xv[m].w, wv[3].z, acc[m].z);
            acc[m].w = fmaf(xv[m].w, wv[3].w, acc[m].w);
        }
    }

#pragma unroll
    for (int m = 0; m < 4; m++) {
        int node = n0 + m;
        if (node < N) {
            us4v hv;
            hv.x = f2bf(acc[m].x);
            hv.y = f2bf(acc[m].y);
            hv.z = f2bf(acc[m].z);
            hv.w = f2bf(acc[m].w);
            __builtin_nontemporal_store(
                hv, (us4v*)&h16[(size_t)node * OUT_CH + cg * 4]);
        }
        float pd = acc[m].x * att_d.x + acc[m].y * att_d.y +
                   acc[m].z * att_d.z + acc[m].w * att_d.w;
        float ps = acc[m].x * att_s.x + acc[m].y * att_s.y +
                   acc[m].z * att_s.z + acc[m].w * att_s.w;
#pragma unroll
        for (int msk = 1; msk < 16; msk <<= 1) {
            pd += __shfl_xor(pd, msk, 64);
            ps += __shfl_xor(ps, msk, 64);
        }
        if (cg == 0 && node < N) { adst[node] = pd; asrc[node] = ps; }
    }
}

// ---------- K2: per-node slot-gather softmax-aggregate + bias + L2 normalize ----------
// 1 wave/node, 2 channels/lane (ushort2), half-waves cover 2 src rows per load.
__global__ __launch_bounds__(256) void k_agg(const unsigned short* __restrict__ h16,
                                             const int* __restrict__ slots,
                                             const int* __restrict__ counts,
                                             const int* __restrict__ oflow_cnt,
                                             const int2* __restrict__ oflow,
                                             const float* __restrict__ asrc,
                                             const float* __restrict__ adst,
                                             const float* __restrict__ bias,
                                             float* __restrict__ out, int N) {
    __shared__ float2 stage[4][64];   // wave-private
    int lane = threadIdx.x & 63;
    int wid = threadIdx.x >> 6;
    int node = blockIdx.x * 4 + wid;
    if (node >= N) return;
    int half = lane >> 5;
    int ch2 = (lane & 31) * 2;

    float aD = adst[node];
    // analytic self loop (h row counted in half 0 only)
    float a = aD + asrc[node];
    a = a > 0.f ? a : NEG_SLOPE * a;
    float w_self = __expf(a);
    unsigned hv = *(const unsigned*)&h16[(size_t)node * OUT_CH + ch2];
    float wse = half ? 0.f : w_self;
    float accx = wse * __uint_as_float(hv << 16);
    float accy = wse * __uint_as_float(hv & 0xFFFF0000u);

    int c = counts[node];           // true degree (may exceed CAP)
    int cs = min(c, CAP);
    int sv = 0;
    float wv = 0.f;
    if (lane < cs) {
        sv = slots[((size_t)node << 6) + lane];   // coalesced 256B
        float av = aD + asrc[sv];                 // parallel gather (L2-hot)
        av = av > 0.f ? av : NEG_SLOPE * av;
        wv = __expf(av);                          // once per edge
    }
    float esum_lane = wv;
    stage[wid][lane] = make_float2(__int_as_float(sv), wv);

    for (int j = 0; j < cs; j += 16) {
#pragma unroll
        for (int k = 0; k < 8; k++) {
            float2 p = stage[wid][j + 2 * k + half];   // 2-addr broadcast, free
            int s = __float_as_int(p.x);
            unsigned v = *(const unsigned*)&h16[((size_t)s << 6) + ch2];
            accx = fmaf(p.y, __uint_as_float(v << 16), accx);
            accy = fmaf(p.y, __uint_as_float(v & 0xFFFF0000u), accy);
        }
    }
    // combine half-waves (even rows in lanes 0-31, odd rows in 32-63)
    accx += __shfl_xor(accx, 32, 64);
    accy += __shfl_xor(accy, 32, 64);
#pragma unroll
    for (int m = 32; m >= 1; m >>= 1) esum_lane += __shfl_xor(esum_lane, m, 64);
    float esum = esum_lane + w_self;

    // cold overflow path (oc == 0 for this input; correct if not)
    int oc = *oflow_cnt;
    if (oc > 0) {
        for (int i = 0; i < oc; i++) {
            int2 e = oflow[i];
            if (e.y == node) {
                float av = aD + asrc[e.x];
                av = av > 0.f ? av : NEG_SLOPE * av;
                float w = __expf(av);
                esum += w;
                unsigned v = *(const unsigned*)&h16[((size_t)e.x << 6) + ch2];
                accx = fmaf(w, __uint_as_float(v << 16), accx);
                accy = fmaf(w, __uint_as_float(v & 0xFFFF0000u), accy);
            }
        }
    }

    float inv = 1.f / (esum + 1e-16f);
    float2 bv = *(const float2*)&bias[ch2];
    float vx = accx * inv + bv.x;
    float vy = accy * inv + bv.y;
    float ss = vx * vx + vy * vy;
#pragma unroll
    for (int m = 16; m >= 1; m >>= 1) ss += __shfl_xor(ss, m, 64);   // within half
    float rinv = 1.f / fmaxf(sqrtf(ss), 1e-12f);
    if (!half)
        *(float2*)&out[(size_t)node * OUT_CH + ch2] = make_float2(vx * rinv, vy * rinv);
}

extern "C" void kernel_launch(void* const* d_in, const int* in_sizes, int n_in,
                              void* d_out, int out_size, void* d_ws, size_t ws_size,
                              hipStream_t stream) {
    const float* x    = (const float*)d_in[0];
    const void*  edges = d_in[1];
    const float* W    = (const float*)d_in[2];
    const float* att  = (const float*)d_in[3];
    const float* bias = (const float*)d_in[4];
    float* out = (float*)d_out;

    const int N = in_sizes[0] / IN_CH;
    const int E = in_sizes[1] / 2;
    const int CHUNK_E = 256 * SCAN_EPT;              // 4096 edges per cs block
    int CHUNKS = (E + CHUNK_E - 1) / CHUNK_E;
    CHUNKS = (CHUNKS + 1) & ~1;                      // even: 2 cs sub-rounds/group
    const int GROUPS = CHUNKS / 2;                   // 98 for E=800000
    const int MMB = (N + 63) / 64;                   // 782
    int extra = MMB - 8 * GROUPS;                    // mm blocks beyond group supply
    if (extra < 0) extra = 0;
    const int grid = GROUPS * 24 + extra;            // 2352

    char* ws = (char*)d_ws;
    size_t off = 0;
    auto alloc = [&](size_t bytes) -> void* {
        void* p = ws + off;
        off += bytes;
        off = (off + 255) & ~(size_t)255;
        return p;
    };
    int*            counts   = (int*)alloc((size_t)(N + 64) * 4);  // +oflow_cnt tail
    int*            slots    = (int*)alloc((size_t)N * CAP * 4);   // 12.8 MB
    int2*           oflow    = (int2*)alloc((size_t)E * 8);        // never used in practice
    unsigned short* h16      = (unsigned short*)alloc((size_t)N * OUT_CH * 2);
    float*          asrc     = (float*)alloc((size_t)N * 4);
    float*          adst     = (float*)alloc((size_t)N * 4);
    int*            oflow_cnt = counts + N;

    hipMemsetAsync(counts, 0, (size_t)(N + 64) * 4, stream);
    k_mm_cs<<<grid, 256, 0, stream>>>(x, W, att, h16, asrc, adst, N,
                                      edges, counts, slots, oflow_cnt,
                                      oflow, E, GROUPS);
    k_agg<<<(N + 3) / 4, 256, 0, stream>>>(h16, slots, counts, oflow_cnt, oflow,
                                           asrc, adst, bias, out, N);
}

// Round 5
// 160.503 us; speedup vs baseline: 1.0732x; 1.0732x over previous
//
#include <hip/hip_runtime.h>
#include <math.h>

#define IN_CH 128
#define OUT_CH 64
#define NEG_SLOPE 0.2f
#define CAP 64         // slots per node; mean degree 16, P(deg>64) ~ 1e-16
#define NSHARD 8       // = XCD count
#define CHUNK_EDGES 4096   // edges per cs chunk (256 thr x 16)

typedef long long ll2 __attribute__((ext_vector_type(2)));

// ---------- bf16 helpers ----------
__device__ __forceinline__ unsigned short f2bf(float f) {
    unsigned u = __float_as_uint(f);
    unsigned r = (u + 0x7FFFu + ((u >> 16) & 1u)) >> 16;   // round-nearest-even
    return (unsigned short)r;
}

// ---------- edge dtype sniff: int64 little-endian => odd int32 words are 0 ----------
__device__ __forceinline__ bool sniff_is64(const void* edges) {
    const unsigned* up = (const unsigned*)edges;
    bool is64 = true;
#pragma unroll
    for (int k = 0; k < 16; k++) is64 = is64 && (up[2 * k + 1] == 0u);
    return is64;
}

// ---------- K1: XCD-local count+scatter (L2-scope atomics) interleaved with mm -------
// R4 decomposition: WRITE 36MB = payload ~10 + ~26MB == 800K x 32B memory-side atomic
// transactions (HIP atomicAdd = agent scope = sc1 = executes at the fabric coherent
// point, ~700cy each). FETCH 50MB = nt edge loads bypassing L3, so the 8x dst rescan
// hit HBM every pass.
// Fix (this round):
//  * cs blocks read their REAL XCD via s_getreg(HW_REG_XCC_ID) and process shard ==
//    XCC_ID, pulling 4096-edge chunks off a per-XCD queue. All updates to a shard's
//    counts/slots then come from exactly one XCD -- so WORKGROUP-scope atomics
//    (global_atomic_add without sc1, executed in the local L2, ~200cy, no memory-side
//    write) are globally correct. Correctness does NOT depend on the dispatch->XCD
//    mapping (shard is derived from the hardware register; any large launch puts
//    blocks on all 8 XCDs, which only affects balance).
//  * edges + x are PLAIN loads now: edge columns (12.8MB) stay L3-resident so the
//    8x rescan is served by Infinity Cache, not HBM; x is L3-resident across iters.
//  * per-XCD queue counters are 64B apart (one line per XCD; no cross-XCD sharing).
__global__ __launch_bounds__(256) void k_mm_cs(
        const float* __restrict__ x, const float* __restrict__ W,
        const float* __restrict__ att, unsigned short* __restrict__ h16,
        float* __restrict__ asrc, float* __restrict__ adst, int N,
        const void* __restrict__ edges, int* __restrict__ counts,
        int* __restrict__ slots, int* __restrict__ oflow_cnt,
        int2* __restrict__ oflow, int E, int mmb, int nchunks,
        int* __restrict__ queues) {
    __shared__ float Ws[IN_CH * OUT_CH];   // 32 KB (mm role); cs reuses word 0
    int t = threadIdx.x;
    int bid = blockIdx.x;
    int total = gridDim.x;
    // Bresenham spread: mm blocks (minority) evenly distributed through the grid
    int mbefore = (int)(((long long)bid * mmb) / total);
    int mafter  = (int)(((long long)(bid + 1) * mmb) / total);
    bool ismm = (mafter != mbefore);
    int id = mbefore;

    if (!ismm) {
        // ----- cs role: drain own-XCD chunk queue -----
        int* chunk_sh = (int*)Ws;   // 4B of the (unused) Ws buffer
        int xcd;
        asm volatile("s_getreg_b32 %0, hwreg(HW_REG_XCC_ID)" : "=s"(xcd));
        xcd &= 7;
        int lo = (int)(((long long)xcd * N) / NSHARD);
        int hi = (int)(((long long)(xcd + 1) * N) / NSHARD);
        bool is64 = sniff_is64(edges);
        for (;;) {
            if (t == 0)
                *chunk_sh = __hip_atomic_fetch_add(queues + xcd * 16, 1,
                                                   __ATOMIC_RELAXED,
                                                   __HIP_MEMORY_SCOPE_WORKGROUP);
            __syncthreads();
            int chunk = *chunk_sh;
            __syncthreads();
            if (chunk >= nchunks) return;

            int base = chunk * CHUNK_EDGES + t * 16;
            int nv = E - base;            // valid edges for this thread
            if (nv <= 0) continue;
            if (nv > 16) nv = 16;
            int dv[16], sv[16];
            if (nv == 16) {
                if (is64) {
                    const ll2* pd = (const ll2*)((const long long*)edges +
                                                 (size_t)E + base);
                    const ll2* ps = (const ll2*)((const long long*)edges + base);
#pragma unroll
                    for (int i = 0; i < 8; i++) {
                        ll2 w = pd[i];
                        dv[2 * i] = (int)w.x; dv[2 * i + 1] = (int)w.y;
                    }
#pragma unroll
                    for (int i = 0; i < 8; i++) {
                        ll2 v = ps[i];
                        sv[2 * i] = (int)v.x; sv[2 * i + 1] = (int)v.y;
                    }
                } else {
                    const int4* pd = (const int4*)((const int*)edges + E + base);
                    const int4* ps = (const int4*)((const int*)edges + base);
#pragma unroll
                    for (int i = 0; i < 4; i++) {
                        int4 w = pd[i];
                        dv[4 * i] = w.x; dv[4 * i + 1] = w.y;
                        dv[4 * i + 2] = w.z; dv[4 * i + 3] = w.w;
                    }
#pragma unroll
                    for (int i = 0; i < 4; i++) {
                        int4 v = ps[i];
                        sv[4 * i] = v.x; sv[4 * i + 1] = v.y;
                        sv[4 * i + 2] = v.z; sv[4 * i + 3] = v.w;
                    }
                }
            } else {
                for (int i = 0; i < 16; i++) {
                    if (i < nv) {
                        if (is64) {
                            dv[i] = (int)((const long long*)edges)[(size_t)E + base + i];
                            sv[i] = (int)((const long long*)edges)[base + i];
                        } else {
                            dv[i] = ((const int*)edges)[E + base + i];
                            sv[i] = ((const int*)edges)[base + i];
                        }
                    } else {
                        dv[i] = -1; sv[i] = 0;
                    }
                }
            }
#pragma unroll
            for (int i = 0; i < 16; i++) {
                int d = dv[i];
                if (d >= lo && d < hi) {
                    // L2-local atomic: all writers of this counter are on this XCD
                    int r = __hip_atomic_fetch_add(counts + d, 1, __ATOMIC_RELAXED,
                                                   __HIP_MEMORY_SCOPE_WORKGROUP);
                    if (r < CAP) {
                        slots[((size_t)d << 6) + r] = sv[i];
                    } else {
                        int p2 = atomicAdd(oflow_cnt, 1);   // rare: device scope
                        oflow[p2] = make_int2(sv[i], d);
                    }
                }
            }
        }
    }

    // ----- mm role: 64 nodes/block, W staged in LDS, plain cacheable x loads -----
    for (int i = t * 4; i < IN_CH * OUT_CH; i += 256 * 4)
        *(float4*)&Ws[i] = *(const float4*)&W[i];
    int cg = t & 15, g = t >> 4;
    float4 att_d = *(const float4*)&att[cg * 4];        // dst half: att[0:64]
    float4 att_s = *(const float4*)&att[64 + cg * 4];   // src half: att[64:128]
    __syncthreads();

    int n0 = id * 64 + g * 4;
    int nn[4];
#pragma unroll
    for (int m = 0; m < 4; m++) nn[m] = min(n0 + m, N - 1);

    float4 acc[4];
#pragma unroll
    for (int m = 0; m < 4; m++) acc[m] = make_float4(0.f, 0.f, 0.f, 0.f);

#pragma unroll 2
    for (int k4 = 0; k4 < IN_CH / 4; k4++) {
        float4 xv[4];
#pragma unroll
        for (int m = 0; m < 4; m++)
            xv[m] = *(const float4*)&x[(size_t)nn[m] * IN_CH + k4 * 4];
        float4 wv[4];
#pragma unroll
        for (int j = 0; j < 4; j++)
            wv[j] = *(const float4*)&Ws[(k4 * 4 + j) * OUT_CH + cg * 4];
#pragma unroll
        for (int m = 0; m < 4; m++) {
            acc[m].x = fmaf(xv[m].x, wv[0].x, acc[m].x);
            acc[m].y = fmaf(xv[m].x, wv[0].y, acc[m].y);
            acc[m].z = fmaf(xv[m].x, wv[0].z, acc[m].z);
            acc[m].w = fmaf(xv[m].x, wv[0].w, acc[m].w);
            acc[m].x = fmaf(xv[m].y, wv[1].x, acc[m].x);
            acc[m].y = fmaf(xv[m].y, wv[1].y, acc[m].y);
            acc[m].z = fmaf(xv[m].y, wv[1].z, acc[m].z);
            acc[m].w = fmaf(xv[m].y, wv[1].w, acc[m].w);
            acc[m].x = fmaf(xv[m].z, wv[2].x, acc[m].x);
            acc[m].y = fmaf(xv[m].z, wv[2].y, acc[m].y);
            acc[m].z = fmaf(xv[m].z, wv[2].z, acc[m].z);
            acc[m].w = fmaf(xv[m].z, wv[2].w, acc[m].w);
            acc[m].x = fmaf(xv[m].w, wv[3].x, acc[m].x);
            acc[m].y = fmaf(xv[m].w, wv[3].y, acc[m].y);
            acc[m].z = fmaf(xv[m].w, wv[3].z, acc[m].z);
            acc[m].w = fmaf(xv[m].w, wv[3].w, acc[m].w);
        }
    }

#pragma unroll
    for (int m = 0; m < 4; m++) {
        int node = n0 + m;
        if (node < N) {
            ushort4 hv;
            hv.x = f2bf(acc[m].x);
            hv.y = f2bf(acc[m].y);
            hv.z = f2bf(acc[m].z);
            hv.w = f2bf(acc[m].w);
            *(ushort4*)&h16[(size_t)node * OUT_CH + cg * 4] = hv;
        }
        float pd = acc[m].x * att_d.x + acc[m].y * att_d.y +
                   acc[m].z * att_d.z + acc[m].w * att_d.w;
        float ps = acc[m].x * att_s.x + acc[m].y * att_s.y +
                   acc[m].z * att_s.z + acc[m].w * att_s.w;
#pragma unroll
        for (int msk = 1; msk < 16; msk <<= 1) {
            pd += __shfl_xor(pd, msk, 64);
            ps += __shfl_xor(ps, msk, 64);
        }
        if (cg == 0 && node < N) { adst[node] = pd; asrc[node] = ps; }
    }
}

// ---------- K2: per-node slot-gather softmax-aggregate + bias + L2 normalize ----------
// 1 wave/node, 2 channels/lane (ushort2), half-waves cover 2 src rows per load.
__global__ __launch_bounds__(256) void k_agg(const unsigned short* __restrict__ h16,
                                             const int* __restrict__ slots,
                                             const int* __restrict__ counts,
                                             const int* __restrict__ oflow_cnt,
                                             const int2* __restrict__ oflow,
                                             const float* __restrict__ asrc,
                                             const float* __restrict__ adst,
                                             const float* __restrict__ bias,
                                             float* __restrict__ out, int N) {
    __shared__ float2 stage[4][64];   // wave-private
    int lane = threadIdx.x & 63;
    int wid = threadIdx.x >> 6;
    int node = blockIdx.x * 4 + wid;
    if (node >= N) return;
    int half = lane >> 5;
    int ch2 = (lane & 31) * 2;

    float aD = adst[node];
    // analytic self loop (h row counted in half 0 only)
    float a = aD + asrc[node];
    a = a > 0.f ? a : NEG_SLOPE * a;
    float w_self = __expf(a);
    unsigned hv = *(const unsigned*)&h16[(size_t)node * OUT_CH + ch2];
    float wse = half ? 0.f : w_self;
    float accx = wse * __uint_as_float(hv << 16);
    float accy = wse * __uint_as_float(hv & 0xFFFF0000u);

    int c = counts[node];           // true degree (may exceed CAP)
    int cs = min(c, CAP);
    int sv = 0;
    float wv = 0.f;
    if (lane < cs) {
        sv = slots[((size_t)node << 6) + lane];   // coalesced 256B
        float av = aD + asrc[sv];                 // parallel gather (L2-hot)
        av = av > 0.f ? av : NEG_SLOPE * av;
        wv = __expf(av);                          // once per edge
    }
    float esum_lane = wv;
    stage[wid][lane] = make_float2(__int_as_float(sv), wv);

    for (int j = 0; j < cs; j += 16) {
#pragma unroll
        for (int k = 0; k < 8; k++) {
            float2 p = stage[wid][j + 2 * k + half];   // 2-addr broadcast, free
            int s = __float_as_int(p.x);
            unsigned v = *(const unsigned*)&h16[((size_t)s << 6) + ch2];
            accx = fmaf(p.y, __uint_as_float(v << 16), accx);
            accy = fmaf(p.y, __uint_as_float(v & 0xFFFF0000u), accy);
        }
    }
    // combine half-waves (even rows in lanes 0-31, odd rows in 32-63)
    accx += __shfl_xor(accx, 32, 64);
    accy += __shfl_xor(accy, 32, 64);
#pragma unroll
    for (int m = 32; m >= 1; m >>= 1) esum_lane += __shfl_xor(esum_lane, m, 64);
    float esum = esum_lane + w_self;

    // cold overflow path (oc == 0 for this input; correct if not)
    int oc = *oflow_cnt;
    if (oc > 0) {
        for (int i = 0; i < oc; i++) {
            int2 e = oflow[i];
            if (e.y == node) {
                float av = aD + asrc[e.x];
                av = av > 0.f ? av : NEG_SLOPE * av;
                float w = __expf(av);
                esum += w;
                unsigned v = *(const unsigned*)&h16[((size_t)e.x << 6) + ch2];
                accx = fmaf(w, __uint_as_float(v << 16), accx);
                accy = fmaf(w, __uint_as_float(v & 0xFFFF0000u), accy);
            }
        }
    }

    float inv = 1.f / (esum + 1e-16f);
    float2 bv = *(const float2*)&bias[ch2];
    float vx = accx * inv + bv.x;
    float vy = accy * inv + bv.y;
    float ss = vx * vx + vy * vy;
#pragma unroll
    for (int m = 16; m >= 1; m >>= 1) ss += __shfl_xor(ss, m, 64);   // within half
    float rinv = 1.f / fmaxf(sqrtf(ss), 1e-12f);
    if (!half)
        *(float2*)&out[(size_t)node * OUT_CH + ch2] = make_float2(vx * rinv, vy * rinv);
}

extern "C" void kernel_launch(void* const* d_in, const int* in_sizes, int n_in,
                              void* d_out, int out_size, void* d_ws, size_t ws_size,
                              hipStream_t stream) {
    const float* x    = (const float*)d_in[0];
    const void*  edges = d_in[1];
    const float* W    = (const float*)d_in[2];
    const float* att  = (const float*)d_in[3];
    const float* bias = (const float*)d_in[4];
    float* out = (float*)d_out;

    const int N = in_sizes[0] / IN_CH;
    const int E = in_sizes[1] / 2;
    const int NCHUNKS = (E + CHUNK_EDGES - 1) / CHUNK_EDGES;   // 196
    const int MMB = (N + 63) / 64;                             // 782
    const int CSB = NSHARD * NCHUNKS;                          // 1568 (1 grab each)
    const int grid = MMB + CSB;                                // 2350

    char* ws = (char*)d_ws;
    size_t off = 0;
    auto alloc = [&](size_t bytes) -> void* {
        void* p = ws + off;
        off += bytes;
        off = (off + 255) & ~(size_t)255;
        return p;
    };
    // counts[N] | oflow_cnt at N | queues at N+64 (8 counters, 64B apart)
    int*            counts   = (int*)alloc((size_t)(N + 256) * 4);
    int*            slots    = (int*)alloc((size_t)N * CAP * 4);   // 12.8 MB
    int2*           oflow    = (int2*)alloc((size_t)E * 8);        // never used in practice
    unsigned short* h16      = (unsigned short*)alloc((size_t)N * OUT_CH * 2);
    float*          asrc     = (float*)alloc((size_t)N * 4);
    float*          adst     = (float*)alloc((size_t)N * 4);
    int*            oflow_cnt = counts + N;
    int*            queues    = counts + N + 64;

    hipMemsetAsync(counts, 0, (size_t)(N + 256) * 4, stream);
    k_mm_cs<<<grid, 256, 0, stream>>>(x, W, att, h16, asrc, adst, N,
                                      edges, counts, slots, oflow_cnt,
                                      oflow, E, MMB, NCHUNKS, queues);
    k_agg<<<(N + 3) / 4, 256, 0, stream>>>(h16, slots, counts, oflow_cnt, oflow,
                                           asrc, adst, bias, out, N);
}